// Round 3
// baseline (884.036 us; speedup 1.0000x reference)
//
#include <hip/hip_runtime.h>

// Model: e = maxpool_L(relu(x @ Wc^T + bc)); feat = [e1-e2, e1*e2];
//        h = tanh(feat @ W1^T + b1); out = h @ W2^T + b2   (all fp32 I/O)
// Sizes: B=2048, L=64, D=300, C=512, H=2048, O=1.
// R6 post-mortem: register-prefetch staging (40 VGPRs held across compute)
//   spilled to scratch: WRITE_SIZE 246MB / +226MB FETCH = spill round-trips.
// R7: stage fp32 x straight to LDS with global_load_lds (zero register
//   payload, zero spill). Wave-specialized: waves 4-7 = producers (their
//   vmcnt queue holds ONLY stage loads -> consumer B-load waits can't drain
//   it), waves 0-3 = consumers (128 channels each, acc[4][8], B from
//   L2-resident WcSwz, fp32->bf16 cvt in-register on the VALU pipe).
//   LDS 157.9KB = 2 x 76928B fp32 tile (double-buffer) + 4KB fs.
//   Row-major fp32 [64][300] tile: row stride 300 words == 12 mod 32 banks
//   -> A-fragment ds_read_b128s are conflict-free (8 lanes/bank minimum).
//   D tail (ks=9) reads <=80B past tile end -> 128B zeroed pad per buffer.

#define B_SZ 2048
#define L_SZ 64
#define D_SZ 300
#define C_SZ 512
#define H_SZ 2048
#define NKC 40            // K-chunks (8 bf16) per row in WcSwz, K padded 300->320
#define TILE_BYTES 76800  // 64 rows x 300 fp32
#define BUFSTRIDE 76928   // + 128B zero pad (tail reads)

typedef __bf16 bf16x8 __attribute__((ext_vector_type(8)));
typedef float f32x4 __attribute__((ext_vector_type(4)));

__device__ __forceinline__ unsigned short f2bf(float f) {
  unsigned int u = __float_as_uint(f);
  u += 0x7fffu + ((u >> 16) & 1u);   // RNE
  return (unsigned short)(u >> 16);
}

// 8 fp32 -> bf16x8 (v_cvt_pk_bf16_f32 pairs, RNE)
__device__ __forceinline__ bf16x8 cvt8(float4 v0, float4 v1) {
  bf16x8 r;
  r[0] = (__bf16)v0.x; r[1] = (__bf16)v0.y; r[2] = (__bf16)v0.z; r[3] = (__bf16)v0.w;
  r[4] = (__bf16)v1.x; r[5] = (__bf16)v1.y; r[6] = (__bf16)v1.z; r[7] = (__bf16)v1.w;
  return r;
}

// async global->LDS, 16B per lane; lds dest = wave-uniform base + lane*16
__device__ __forceinline__ void gload_lds16(const float* g, void* l) {
  __builtin_amdgcn_global_load_lds(
      (const __attribute__((address_space(1))) void*)g,
      (__attribute__((address_space(3))) void*)l, 16, 0, 0);
}

// ---- kernel 0: build swizzled bf16 weights + init out = b2.
// WcSwz[(c/16)*40 + kc][l16=c%16][8]  (zero-pad k>=300)
// W1Swz[(j/16)*128 + kc][l16=j%16][8]
__global__ __launch_bounds__(256)
void convert_kernel(const float* __restrict__ Wc, const float* __restrict__ W1,
                    const float* __restrict__ b2,
                    unsigned short* __restrict__ WcSwz, unsigned short* __restrict__ W1Swz,
                    float* __restrict__ out) {
  int id = blockIdx.x * 256 + threadIdx.x;
  if (id < B_SZ) out[id] = b2[0];             // fc1 accumulates into out
  if (id < C_SZ * NKC) {                      // 20480 threads: (c, kc)
    int c = id / NKC, kc = id - c * NKC;
    unsigned short tmp[8];
    #pragma unroll
    for (int i = 0; i < 8; ++i) {
      int k = kc * 8 + i;
      tmp[i] = (k < D_SZ) ? f2bf(Wc[c * D_SZ + k]) : (unsigned short)0;
    }
    unsigned short* dst = WcSwz + (((c >> 4) * NKC + kc) * 16 + (c & 15)) * 8;
    *reinterpret_cast<uint4*>(dst) = *reinterpret_cast<uint4*>(tmp);
    return;
  }
  id -= C_SZ * NKC;
  if (id < H_SZ * 128) {                      // 262144 threads: (j, kc)
    int j = id >> 7, kc = id & 127;
    const float* src = W1 + (size_t)j * 1024 + kc * 8;
    unsigned short tmp[8];
    #pragma unroll
    for (int i = 0; i < 8; ++i) tmp[i] = f2bf(src[i]);
    unsigned short* dst = W1Swz + (((j >> 4) * 128 + kc) * 16 + (j & 15)) * 8;
    *reinterpret_cast<uint4*>(dst) = *reinterpret_cast<uint4*>(tmp);
  }
}

// ---- kernel 1: persistent encode + feat. 256 blocks (1/CU), 512 threads.
// Block handles b = bid + 256*i, i<8; per b two tiles (z=0,1), 16 tiles,
// fp32 double-buffered LDS. Waves 0-3 consume (128 ch each), 4-7 produce.
__global__ __launch_bounds__(512, 2)
void encode_feat_kernel(const float* __restrict__ x1, const float* __restrict__ x2,
                        const unsigned short* __restrict__ WcSwz,
                        const float* __restrict__ bc,
                        unsigned short* __restrict__ featSwz) {
  __shared__ __align__(16) char lds_pool[2 * BUFSTRIDE + 4096];  // 157,952 B
  float* fs = reinterpret_cast<float*>(lds_pool + 2 * BUFSTRIDE);
  const int tid = threadIdx.x;
  const int wave = tid >> 6, lane = tid & 63;
  const int l16 = lane & 15, quad = lane >> 4;

  // zero the 128B tail pad of each buffer (ks=9 row-63 reads land here)
  if (tid < 16) {
    int bbuf = tid >> 3, o = (tid & 7) * 16;
    *reinterpret_cast<uint4*>(lds_pool + bbuf * BUFSTRIDE + TILE_BYTES + o) =
        make_uint4(0, 0, 0, 0);
  }

  float bias[8], e1[8];
  if (wave < 4) {
    #pragma unroll
    for (int nt = 0; nt < 8; ++nt) bias[nt] = bc[wave * 128 + nt * 16 + l16];
  } else {
    // producers: stage tile 0 into buffer 0 (75 x 1KB wave-issues, 4 waves)
    const float* xb = x1 + (size_t)blockIdx.x * (L_SZ * D_SZ);
    for (int j = wave - 4; j < 75; j += 4)
      gload_lds16(xb + j * 256 + lane * 4, lds_pool + j * 1024);
    asm volatile("s_waitcnt vmcnt(0)" ::: "memory");
  }
  __syncthreads();

  const unsigned short* wcb =
      WcSwz + (size_t)(wave * 8) * 5120 + quad * 128 + l16 * 8;  // consumer B base
  int buf = 0;

  for (int t = 0; t < 16; ++t) {
    if (wave >= 4) {
      // ---- producers: stage tile t+1 into buf^1 (their vmcnt queue only)
      if (t < 15) {
        int tn = t + 1;
        const float* xb = ((tn & 1) ? x2 : x1) +
                          (size_t)(blockIdx.x + (tn >> 1) * 256) * (L_SZ * D_SZ);
        char* dst = lds_pool + (buf ^ 1) * BUFSTRIDE;
        for (int j = wave - 4; j < 75; j += 4)
          gload_lds16(xb + j * 256 + lane * 4, dst + j * 1024);
      }
      asm volatile("s_waitcnt vmcnt(0)" ::: "memory");
    } else {
      // ---- consumers: M=64 x N=128 x K=320 on buf; B from L2 (WcSwz)
      const char* xb = lds_pool + buf * BUFSTRIDE;
      f32x4 acc[4][8];
      #pragma unroll
      for (int mt = 0; mt < 4; ++mt)
        #pragma unroll
        for (int nt = 0; nt < 8; ++nt)
          #pragma unroll
          for (int r = 0; r < 4; ++r) acc[mt][nt][r] = 0.f;

      #pragma unroll
      for (int ks = 0; ks < 10; ++ks) {
        bf16x8 a[4];
        #pragma unroll
        for (int mt = 0; mt < 4; ++mt) {
          const char* p = xb + (mt * 16 + l16) * 1200 + ks * 128 + quad * 32;
          float4 v0 = *reinterpret_cast<const float4*>(p);
          float4 v1 = *reinterpret_cast<const float4*>(p + 16);
          a[mt] = cvt8(v0, v1);
        }
        #pragma unroll
        for (int nt = 0; nt < 8; ++nt) {
          bf16x8 bw = *reinterpret_cast<const bf16x8*>(wcb + nt * 5120 + ks * 512);
          #pragma unroll
          for (int mt = 0; mt < 4; ++mt)
            acc[mt][nt] =
                __builtin_amdgcn_mfma_f32_16x16x32_bf16(a[mt], bw, acc[mt][nt], 0, 0, 0);
        }
      }

      // epilogue: +bias, relu, max over 64 words (D row = quad*4+r, col = l16)
      #pragma unroll
      for (int nt = 0; nt < 8; ++nt) {
        float v = 0.f;
        #pragma unroll
        for (int mt = 0; mt < 4; ++mt)
          #pragma unroll
          for (int r = 0; r < 4; ++r)
            v = fmaxf(v, acc[mt][nt][r] + bias[nt]);
        v = fmaxf(v, __shfl_xor(v, 16));
        v = fmaxf(v, __shfl_xor(v, 32));
        if (!(t & 1)) {
          e1[nt] = v;
        } else if (quad == 0) {
          int c = wave * 128 + nt * 16 + l16;
          fs[c]       = e1[nt] - v;
          fs[512 + c] = e1[nt] * v;
        }
      }
    }

    __syncthreads();  // stage(t+1) landed; fs visible; buf reads done

    // feat pack by producer waves 4-5 (keeps consumer vmcnt queues pure-B)
    if ((t & 1) && tid >= 256 && tid < 384) {
      int i = tid - 256;
      int b = blockIdx.x + (t >> 1) * 256;
      unsigned short tmp[8];
      #pragma unroll
      for (int k2 = 0; k2 < 8; ++k2) tmp[k2] = f2bf(fs[i * 8 + k2]);
      *reinterpret_cast<uint4*>(featSwz + (((b >> 4) * 128 + i) * 16 + (b & 15)) * 8) =
          *reinterpret_cast<uint4*>(tmp);
    }
    buf ^= 1;
  }
}

// ---- kernel 2: fc1+fc2 fused. pre = feat @ W1^T + b1; t = tanh(pre);
// out[b] += sum over this wave's 32 j-cols of t * W2[j]  (atomic).
__global__ __launch_bounds__(256, 4)
void fc1_kernel(const unsigned short* __restrict__ featSwz,
                const unsigned short* __restrict__ W1Swz,
                const float* __restrict__ b1, const float* __restrict__ W2,
                float* __restrict__ out) {
  const int mbase = blockIdx.x * 32;
  const int tid = threadIdx.x;
  const int wave = tid >> 6, lane = tid & 63;
  const int l16 = lane & 15, quad = lane >> 4;
  const int nbase = blockIdx.y * 128 + wave * 32;

  f32x4 acc[2][2];
  #pragma unroll
  for (int mt = 0; mt < 2; ++mt)
    #pragma unroll
    for (int nt = 0; nt < 2; ++nt)
      #pragma unroll
      for (int r = 0; r < 4; ++r) acc[mt][nt][r] = 0.f;

  #pragma unroll 4
  for (int ks = 0; ks < 32; ++ks) {
    bf16x8 a[2], bw[2];
    #pragma unroll
    for (int mt = 0; mt < 2; ++mt)
      a[mt] = *reinterpret_cast<const bf16x8*>(
          featSwz + (((size_t)(blockIdx.x * 2 + mt) * 128 + ks * 4 + quad) * 16 + l16) * 8);
    #pragma unroll
    for (int nt = 0; nt < 2; ++nt)
      bw[nt] = *reinterpret_cast<const bf16x8*>(
          W1Swz + (((size_t)(blockIdx.y * 8 + wave * 2 + nt) * 128 + ks * 4 + quad) * 16 + l16) * 8);
    #pragma unroll
    for (int mt = 0; mt < 2; ++mt)
      #pragma unroll
      for (int nt = 0; nt < 2; ++nt)
        acc[mt][nt] = __builtin_amdgcn_mfma_f32_16x16x32_bf16(a[mt], bw[nt], acc[mt][nt], 0, 0, 0);
  }

  // epilogue: tanh in fp32, dot with W2, reduce over this wave's 32 j-cols
  float c[2][4];
  #pragma unroll
  for (int mt = 0; mt < 2; ++mt)
    #pragma unroll
    for (int r = 0; r < 4; ++r) c[mt][r] = 0.f;

  #pragma unroll
  for (int nt = 0; nt < 2; ++nt) {
    int j = nbase + nt * 16 + l16;
    float bias = b1[j];
    float w2 = W2[j];
    #pragma unroll
    for (int mt = 0; mt < 2; ++mt)
      #pragma unroll
      for (int r = 0; r < 4; ++r) {
        float pre = acc[mt][nt][r] + bias;
        pre = fminf(fmaxf(pre, -15.f), 15.f);
        float ex = __expf(2.f * pre);
        c[mt][r] += w2 * ((ex - 1.f) / (ex + 1.f));
      }
  }
  #pragma unroll
  for (int off = 1; off <= 8; off <<= 1)
    #pragma unroll
    for (int mt = 0; mt < 2; ++mt)
      #pragma unroll
      for (int r = 0; r < 4; ++r)
        c[mt][r] += __shfl_xor(c[mt][r], off);

  if (l16 == 0) {
    #pragma unroll
    for (int mt = 0; mt < 2; ++mt)
      #pragma unroll
      for (int r = 0; r < 4; ++r) {
        int brow = mbase + mt * 16 + quad * 4 + r;
        atomicAdd(&out[brow], c[mt][r]);
      }
  }
}

extern "C" void kernel_launch(void* const* d_in, const int* in_sizes, int n_in,
                              void* d_out, int out_size, void* d_ws, size_t ws_size,
                              hipStream_t stream) {
  const float* x1 = (const float*)d_in[0];
  const float* x2 = (const float*)d_in[1];
  const float* Wc = (const float*)d_in[2];
  const float* bc = (const float*)d_in[3];
  const float* W1 = (const float*)d_in[4];
  const float* b1 = (const float*)d_in[5];
  const float* W2 = (const float*)d_in[6];
  const float* b2 = (const float*)d_in[7];

  char* ws = (char*)d_ws;
  unsigned short* WcSwz   = (unsigned short*)(ws);             // 327,680 B
  unsigned short* W1Swz   = (unsigned short*)(ws + 327680);    // 4,194,304 B
  unsigned short* featSwz = (unsigned short*)(ws + 4521984);   // 4,194,304 B
  // total: 8,716,288 B

  {
    int total = C_SZ * NKC + H_SZ * 128;  // 282,624
    convert_kernel<<<(total + 255) / 256, 256, 0, stream>>>(Wc, W1, b2, WcSwz, W1Swz,
                                                            (float*)d_out);
  }
  encode_feat_kernel<<<256, 512, 0, stream>>>(x1, x2, WcSwz, bc, featSwz);
  fc1_kernel<<<dim3(B_SZ / 32, H_SZ / 128), 256, 0, stream>>>(featSwz, W1Swz, b1, W2,
                                                              (float*)d_out);
}

// Round 4
// 455.650 us; speedup vs baseline: 1.9402x; 1.9402x over previous
//
#include <hip/hip_runtime.h>

// Model: e = maxpool_L(relu(x @ Wc^T + bc)); feat = [e1-e2, e1*e2];
//        h = tanh(feat @ W1^T + b1); out = h @ W2^T + b2   (all fp32 I/O)
// Sizes: B=2048, L=64, D=300, C=512, H=2048, O=1.
// R7 post-mortem: B-loads from global thrashed L2 (x-stream evicts WcSwz:
//   2.4MB/tile-period per XCD through 4MB L2) -> consumers stalled at HBM
//   latency on B; FETCH +109MB, 5% MfmaUtil.
// R8: weights RESIDENT IN REGISTERS. Each of 8 waves owns 64 channels:
//   B = 40 bf16x8 = 160 VGPRs, loaded once from WcSwz at start. The maxpool
//   over words lets each wave process its 4 M-subtiles sequentially reusing
//   one 16-VGPR accumulator (fold relu+bias+max per mt). Inner loop has ZERO
//   global loads -> only stage gload_lds in the vmcnt queue (m97 pattern:
//   issue stage(t+1), compute(t), barrier). x fp32 double-buffer 2x76.9KB.
//   Phase budget: HBM 7500cy >> LDS-read 5000cy >> MFMA 1550cy -> HBM-bound.

#define B_SZ 2048
#define L_SZ 64
#define D_SZ 300
#define C_SZ 512
#define H_SZ 2048
#define NKC 40            // K-chunks (8 bf16) per row in WcSwz, K padded 300->320
#define TILE_BYTES 76800  // 64 rows x 300 fp32
#define BUFSTRIDE 76928   // + 128B zero pad (ks=9 tail reads of row 63)

typedef __bf16 bf16x8 __attribute__((ext_vector_type(8)));
typedef float f32x4 __attribute__((ext_vector_type(4)));

__device__ __forceinline__ unsigned short f2bf(float f) {
  unsigned int u = __float_as_uint(f);
  u += 0x7fffu + ((u >> 16) & 1u);   // RNE
  return (unsigned short)(u >> 16);
}

// 8 fp32 -> bf16x8 (v_cvt_pk_bf16_f32 pairs, RNE)
__device__ __forceinline__ bf16x8 cvt8(float4 v0, float4 v1) {
  bf16x8 r;
  r[0] = (__bf16)v0.x; r[1] = (__bf16)v0.y; r[2] = (__bf16)v0.z; r[3] = (__bf16)v0.w;
  r[4] = (__bf16)v1.x; r[5] = (__bf16)v1.y; r[6] = (__bf16)v1.z; r[7] = (__bf16)v1.w;
  return r;
}

// async global->LDS, 16B per lane; lds dest = wave-uniform base + lane*16
__device__ __forceinline__ void gload_lds16(const float* g, void* l) {
  __builtin_amdgcn_global_load_lds(
      (const __attribute__((address_space(1))) void*)g,
      (__attribute__((address_space(3))) void*)l, 16, 0, 0);
}

// ---- kernel 0: build swizzled bf16 weights + init out = b2.
// WcSwz[(c/16)*40 + kc][l16=c%16][8]  (zero-pad k>=300)
// W1Swz[(j/16)*128 + kc][l16=j%16][8]
__global__ __launch_bounds__(256)
void convert_kernel(const float* __restrict__ Wc, const float* __restrict__ W1,
                    const float* __restrict__ b2,
                    unsigned short* __restrict__ WcSwz, unsigned short* __restrict__ W1Swz,
                    float* __restrict__ out) {
  int id = blockIdx.x * 256 + threadIdx.x;
  if (id < B_SZ) out[id] = b2[0];             // fc1 accumulates into out
  if (id < C_SZ * NKC) {                      // 20480 threads: (c, kc)
    int c = id / NKC, kc = id - c * NKC;
    unsigned short tmp[8];
    #pragma unroll
    for (int i = 0; i < 8; ++i) {
      int k = kc * 8 + i;
      tmp[i] = (k < D_SZ) ? f2bf(Wc[c * D_SZ + k]) : (unsigned short)0;
    }
    unsigned short* dst = WcSwz + (((c >> 4) * NKC + kc) * 16 + (c & 15)) * 8;
    *reinterpret_cast<uint4*>(dst) = *reinterpret_cast<uint4*>(tmp);
    return;
  }
  id -= C_SZ * NKC;
  if (id < H_SZ * 128) {                      // 262144 threads: (j, kc)
    int j = id >> 7, kc = id & 127;
    const float* src = W1 + (size_t)j * 1024 + kc * 8;
    unsigned short tmp[8];
    #pragma unroll
    for (int i = 0; i < 8; ++i) tmp[i] = f2bf(src[i]);
    unsigned short* dst = W1Swz + (((j >> 4) * 128 + kc) * 16 + (j & 15)) * 8;
    *reinterpret_cast<uint4*>(dst) = *reinterpret_cast<uint4*>(tmp);
  }
}

// ---- kernel 1: persistent encode + feat. 256 blocks (1/CU), 512 threads.
// Block handles b = bid + 256*i, i<8; per b two tiles (z=0,1), 16 tiles,
// fp32 double-buffered LDS. All 8 waves stage AND compute; wave w owns
// channels [w*64, w*64+64) with weights resident in 160 VGPRs.
__global__ __launch_bounds__(512, 2)
void encode_feat_kernel(const float* __restrict__ x1, const float* __restrict__ x2,
                        const unsigned short* __restrict__ WcSwz,
                        const float* __restrict__ bc,
                        unsigned short* __restrict__ featSwz) {
  __shared__ __align__(16) char lds_pool[2 * BUFSTRIDE + 4096];  // 157,952 B
  float* fs = reinterpret_cast<float*>(lds_pool + 2 * BUFSTRIDE);
  const int tid = threadIdx.x;
  const int wave = tid >> 6, lane = tid & 63;
  const int l16 = lane & 15, quad = lane >> 4;

  // zero the 128B tail pad of each buffer (ks=9 row-63 reads land here)
  if (tid < 16) {
    int bbuf = tid >> 3, o = (tid & 7) * 16;
    *reinterpret_cast<uint4*>(lds_pool + bbuf * BUFSTRIDE + TILE_BYTES + o) =
        make_uint4(0, 0, 0, 0);
  }

  // resident weights: breg[nt][ks] for channels wave*64 + nt*16 + l16,
  // k-slice = ks*32 + quad*8 .. +8  (WcSwz chtile = wave*4+nt, kc = ks*4+quad)
  bf16x8 breg[4][10];
  #pragma unroll
  for (int nt = 0; nt < 4; ++nt)
    #pragma unroll
    for (int ks = 0; ks < 10; ++ks)
      breg[nt][ks] = *reinterpret_cast<const bf16x8*>(
          WcSwz + (size_t)(wave * 4 + nt) * 5120 + (ks * 4 + quad) * 128 + l16 * 8);

  float bias[4];
  #pragma unroll
  for (int nt = 0; nt < 4; ++nt) bias[nt] = bc[wave * 64 + nt * 16 + l16];

  // stage tile 0 (t=0 -> z=0, b=bid): 75 x 1KB wave-issues split over 8 waves
  {
    const float* xb = x1 + (size_t)blockIdx.x * (L_SZ * D_SZ);
    for (int j = wave; j < 75; j += 8)
      gload_lds16(xb + j * 256 + lane * 4, lds_pool + j * 1024);
  }
  asm volatile("s_waitcnt vmcnt(0)" ::: "memory");
  __syncthreads();

  float e1[4];
  int buf = 0;

  for (int t = 0; t < 16; ++t) {
    // issue stage of tile t+1 into buf^1 (drained by compiler before barrier)
    if (t < 15) {
      int tn = t + 1;
      const float* xb = ((tn & 1) ? x2 : x1) +
                        (size_t)(blockIdx.x + (tn >> 1) * 256) * (L_SZ * D_SZ);
      char* dst = lds_pool + (buf ^ 1) * BUFSTRIDE;
      for (int j = wave; j < 75; j += 8)
        gload_lds16(xb + j * 256 + lane * 4, dst + j * 1024);
    }

    // compute tile t from buf: 4 M-subtiles sequentially, acc reused
    const char* xt = lds_pool + buf * BUFSTRIDE;
    float erun[4] = {0.f, 0.f, 0.f, 0.f};   // relu floor
    #pragma unroll
    for (int mt = 0; mt < 4; ++mt) {
      f32x4 acc[4];
      #pragma unroll
      for (int nt = 0; nt < 4; ++nt)
        #pragma unroll
        for (int r = 0; r < 4; ++r) acc[nt][r] = 0.f;
      #pragma unroll
      for (int ks = 0; ks < 10; ++ks) {
        const char* p = xt + (mt * 16 + l16) * 1200 + ks * 128 + quad * 32;
        float4 v0 = *reinterpret_cast<const float4*>(p);
        float4 v1 = *reinterpret_cast<const float4*>(p + 16);
        bf16x8 a = cvt8(v0, v1);
        #pragma unroll
        for (int nt = 0; nt < 4; ++nt)
          acc[nt] = __builtin_amdgcn_mfma_f32_16x16x32_bf16(a, breg[nt][ks], acc[nt], 0, 0, 0);
      }
      #pragma unroll
      for (int nt = 0; nt < 4; ++nt)
        #pragma unroll
        for (int r = 0; r < 4; ++r)
          erun[nt] = fmaxf(erun[nt], acc[nt][r] + bias[nt]);
    }

    // finish max over words (rows live in quad x r), then e1/feat
    #pragma unroll
    for (int nt = 0; nt < 4; ++nt) {
      float v = erun[nt];
      v = fmaxf(v, __shfl_xor(v, 16));
      v = fmaxf(v, __shfl_xor(v, 32));
      if (!(t & 1)) {
        e1[nt] = v;
      } else if (quad == 0) {
        int c = wave * 64 + nt * 16 + l16;
        fs[c]       = e1[nt] - v;
        fs[512 + c] = e1[nt] * v;
      }
    }

    __syncthreads();  // staged tile landed; buf reads done; fs visible

    if ((t & 1) && tid < 128) {  // pack feat of b into featSwz (kc = tid)
      int b = blockIdx.x + (t >> 1) * 256;
      unsigned short tmp[8];
      #pragma unroll
      for (int i = 0; i < 8; ++i) tmp[i] = f2bf(fs[tid * 8 + i]);
      *reinterpret_cast<uint4*>(featSwz + (((b >> 4) * 128 + tid) * 16 + (b & 15)) * 8) =
          *reinterpret_cast<uint4*>(tmp);
    }
    buf ^= 1;
  }
}

// ---- kernel 2: fc1+fc2 fused. pre = feat @ W1^T + b1; t = tanh(pre);
// out[b] += sum over this wave's 32 j-cols of t * W2[j]  (atomic).
__global__ __launch_bounds__(256, 4)
void fc1_kernel(const unsigned short* __restrict__ featSwz,
                const unsigned short* __restrict__ W1Swz,
                const float* __restrict__ b1, const float* __restrict__ W2,
                float* __restrict__ out) {
  const int mbase = blockIdx.x * 32;
  const int tid = threadIdx.x;
  const int wave = tid >> 6, lane = tid & 63;
  const int l16 = lane & 15, quad = lane >> 4;
  const int nbase = blockIdx.y * 128 + wave * 32;

  f32x4 acc[2][2];
  #pragma unroll
  for (int mt = 0; mt < 2; ++mt)
    #pragma unroll
    for (int nt = 0; nt < 2; ++nt)
      #pragma unroll
      for (int r = 0; r < 4; ++r) acc[mt][nt][r] = 0.f;

  #pragma unroll 4
  for (int ks = 0; ks < 32; ++ks) {
    bf16x8 a[2], bw[2];
    #pragma unroll
    for (int mt = 0; mt < 2; ++mt)
      a[mt] = *reinterpret_cast<const bf16x8*>(
          featSwz + (((size_t)(blockIdx.x * 2 + mt) * 128 + ks * 4 + quad) * 16 + l16) * 8);
    #pragma unroll
    for (int nt = 0; nt < 2; ++nt)
      bw[nt] = *reinterpret_cast<const bf16x8*>(
          W1Swz + (((size_t)(blockIdx.y * 8 + wave * 2 + nt) * 128 + ks * 4 + quad) * 16 + l16) * 8);
    #pragma unroll
    for (int mt = 0; mt < 2; ++mt)
      #pragma unroll
      for (int nt = 0; nt < 2; ++nt)
        acc[mt][nt] = __builtin_amdgcn_mfma_f32_16x16x32_bf16(a[mt], bw[nt], acc[mt][nt], 0, 0, 0);
  }

  // epilogue: tanh in fp32, dot with W2, reduce over this wave's 32 j-cols
  float c[2][4];
  #pragma unroll
  for (int mt = 0; mt < 2; ++mt)
    #pragma unroll
    for (int r = 0; r < 4; ++r) c[mt][r] = 0.f;

  #pragma unroll
  for (int nt = 0; nt < 2; ++nt) {
    int j = nbase + nt * 16 + l16;
    float bias = b1[j];
    float w2 = W2[j];
    #pragma unroll
    for (int mt = 0; mt < 2; ++mt)
      #pragma unroll
      for (int r = 0; r < 4; ++r) {
        float pre = acc[mt][nt][r] + bias;
        pre = fminf(fmaxf(pre, -15.f), 15.f);
        float ex = __expf(2.f * pre);
        c[mt][r] += w2 * ((ex - 1.f) / (ex + 1.f));
      }
  }
  #pragma unroll
  for (int off = 1; off <= 8; off <<= 1)
    #pragma unroll
    for (int mt = 0; mt < 2; ++mt)
      #pragma unroll
      for (int r = 0; r < 4; ++r)
        c[mt][r] += __shfl_xor(c[mt][r], off);

  if (l16 == 0) {
    #pragma unroll
    for (int mt = 0; mt < 2; ++mt)
      #pragma unroll
      for (int r = 0; r < 4; ++r) {
        int brow = mbase + mt * 16 + quad * 4 + r;
        atomicAdd(&out[brow], c[mt][r]);
      }
  }
}

extern "C" void kernel_launch(void* const* d_in, const int* in_sizes, int n_in,
                              void* d_out, int out_size, void* d_ws, size_t ws_size,
                              hipStream_t stream) {
  const float* x1 = (const float*)d_in[0];
  const float* x2 = (const float*)d_in[1];
  const float* Wc = (const float*)d_in[2];
  const float* bc = (const float*)d_in[3];
  const float* W1 = (const float*)d_in[4];
  const float* b1 = (const float*)d_in[5];
  const float* W2 = (const float*)d_in[6];
  const float* b2 = (const float*)d_in[7];

  char* ws = (char*)d_ws;
  unsigned short* WcSwz   = (unsigned short*)(ws);             // 327,680 B
  unsigned short* W1Swz   = (unsigned short*)(ws + 327680);    // 4,194,304 B
  unsigned short* featSwz = (unsigned short*)(ws + 4521984);   // 4,194,304 B
  // total: 8,716,288 B

  {
    int total = C_SZ * NKC + H_SZ * 128;  // 282,624
    convert_kernel<<<(total + 255) / 256, 256, 0, stream>>>(Wc, W1, b2, WcSwz, W1Swz,
                                                            (float*)d_out);
  }
  encode_feat_kernel<<<256, 512, 0, stream>>>(x1, x2, WcSwz, bc, featSwz);
  fc1_kernel<<<dim3(B_SZ / 32, H_SZ / 128), 256, 0, stream>>>(featSwz, W1Swz, b1, W2,
                                                              (float*)d_out);
}